// Round 1
// baseline (532.818 us; speedup 1.0000x reference)
//
#include <hip/hip_runtime.h>

// RelativePositionEncoding: O[i,j,c] = Wt[dres][c] + Wt[66+dtok][c]
//                                    + same_entity*Wt[132][c] + Wt[133+dchain][c]
// Wt[b][c] = W[c*139 + b]. Pure gather+add; store-BW bound (537 MB fp32 out,
// floor ~85 us @ 6.3 TB/s).
//
// R5->R6: rocprof showed relpos_kernel absent from top-5 (all harness fills),
// so kernel itself ~190 us vs 85 us store floor. Remaining cost was prologue
// replication: 2048 blocks each re-staging W (35.6 KB) + 1024-j pack pass.
// Changes: (1) merge the two c-half blocks -> 512 threads cover full C_Z=128,
// so each wave's NT store is one contiguous 512 B segment per j; (2) NI=2
// i-values per block -> grid 2048->512, 4x fewer prologues and 4x less W
// re-staging; per-j attributes held in registers across the i-loop so pack
// recompute is VALU-only. LDS = 139*132*4 + 4 KB = 77.5 KB -> 2 blocks/CU,
// 16 waves/CU. Read conflicts: stride 132 words -> 2 rows/wave/operand,
// worst 2-way (free). Write-side transpose stays 8-way (cheap, 4x fewer).

#define R_MAX 32
#define NO_BINS 139
#define C_Z 128
#define N_MAX 1024     // harness N = 1024
#define WSTRIDE 132    // padded LDS row stride (words); 132%32=4, 16B-aligned rows
#define NI 2           // i-rows per block
#define NTHREADS 512

typedef float v4f __attribute__((ext_vector_type(4)));

__device__ __forceinline__ int make_pack(int ai, int ri, int ei, int ti, int si,
                                         int aj, int rj, int ej, int tj, int sj)
{
    const bool sc = (ai == aj);
    const bool sr = (ri == rj);
    const bool se = (ei == ej);

    int dr = min(max(ri - rj + R_MAX, 0), 2 * R_MAX);
    if (!sc) dr = 2 * R_MAX + 1;                    // 65
    int dt = min(max(ti - tj + R_MAX, 0), 2 * R_MAX);
    if (!(sc && sr)) dt = 2 * R_MAX + 1;            // 65
    int dc = min(max(si - sj + 2, 0), 4);
    if (!se) dc = 5;

    return dr | ((66 + dt) << 7) | ((133 + dc) << 15) | ((se ? 1 : 0) << 23);
}

__global__ __launch_bounds__(NTHREADS) void relpos_kernel(
    const int* __restrict__ asym, const int* __restrict__ res,
    const int* __restrict__ ent,  const int* __restrict__ tok,
    const int* __restrict__ sym,  const float* __restrict__ W,
    float* __restrict__ out, int N)
{
    __shared__ float wt[NO_BINS * WSTRIDE];  // 73,392 B: wt[b*132 + c]
    __shared__ int   jb_pack[N_MAX];         //  4,096 B

    const int tid = threadIdx.x;
    const int i0  = blockIdx.x * NI;

    // --- stage full W: coalesced float4 reads of contiguous W[c*139+b],
    //     transposed padded LDS writes (8-way write conflict, cheap) ---
    for (int q = tid; q < (C_Z * NO_BINS) / 4; q += NTHREADS) {  // 4448 float4
        const v4f v = *(const v4f*)(W + 4 * q);
        const int e = 4 * q;
#pragma unroll
        for (int k = 0; k < 4; ++k) {
            const int ee = e + k;
            const int c  = ee / NO_BINS;        // magic-mul div
            const int b  = ee - c * NO_BINS;
            wt[b * WSTRIDE + c] = v[k];
        }
    }

    // --- per-thread j attributes held in registers across the i-loop ---
    const int j0 = tid, j1 = tid + NTHREADS;
    const int rj0 = res[j0], tj0 = tok[j0], aj0 = asym[j0],
              ej0 = ent[j0], sj0 = sym[j0];
    int rj1 = 0, tj1 = 0, aj1 = 0, ej1 = 0, sj1 = 0;
    const bool has1 = (j1 < N);
    if (has1) { rj1 = res[j1]; tj1 = tok[j1]; aj1 = asym[j1];
                ej1 = ent[j1]; sj1 = sym[j1]; }

    const int c4 = (tid & 31) * 4;  // lane's 4-float slice within the 128-c row
    const int jl = tid >> 5;        // 0..15: j within chunk

    for (int ii = 0; ii < NI; ++ii) {
        const int i = i0 + ii;
        if (i >= N) break;

        // i-side scalars (block-uniform)
        const int ai = asym[i], ri = res[i], ei = ent[i], ti = tok[i], si = sym[i];

        __syncthreads();  // wt staged (ii==0) / prior main-loop pack reads done
        jb_pack[j0] = make_pack(ai, ri, ei, ti, si, aj0, rj0, ej0, tj0, sj0);
        if (has1)
            jb_pack[j1] = make_pack(ai, ri, ei, ti, si, aj1, rj1, ej1, tj1, sj1);
        __syncthreads();

        const v4f entv = *(const v4f*)&wt[132 * WSTRIDE + c4];
        float* po = out + ((size_t)i * N + jl) * C_Z + c4;

        // --- main loop: LDS-only reads, one contiguous nontemporal store ---
        for (int jb = 0; jb < N; jb += 16) {
            const int pk   = jb_pack[jb + jl];   // broadcast within 32-lane group
            const int rowR = pk & 127;
            const int rowT = (pk >> 7) & 255;
            const int rowC = (pk >> 15) & 255;
            const float se = (pk >> 23) ? 1.0f : 0.0f;

            const v4f r0 = *(const v4f*)&wt[rowR * WSTRIDE + c4];
            const v4f t0 = *(const v4f*)&wt[rowT * WSTRIDE + c4];
            const v4f k0 = *(const v4f*)&wt[rowC * WSTRIDE + c4];

            v4f o;
            o.x = fmaf(se, entv.x, r0.x + t0.x + k0.x);
            o.y = fmaf(se, entv.y, r0.y + t0.y + k0.y);
            o.z = fmaf(se, entv.z, r0.z + t0.z + k0.z);
            o.w = fmaf(se, entv.w, r0.w + t0.w + k0.w);

            // 16B/lane; 32 lanes/j -> 512B fully-contiguous per j; nt: no L2 retention
            __builtin_nontemporal_store(o, (v4f*)po);
            po += 16 * C_Z;
        }
    }
}

extern "C" void kernel_launch(void* const* d_in, const int* in_sizes, int n_in,
                              void* d_out, int out_size, void* d_ws, size_t ws_size,
                              hipStream_t stream) {
    const int*   asym = (const int*)d_in[0];
    const int*   res  = (const int*)d_in[1];
    const int*   ent  = (const int*)d_in[2];
    const int*   tok  = (const int*)d_in[3];
    const int*   sym  = (const int*)d_in[4];
    const float* W    = (const float*)d_in[5];
    float* out = (float*)d_out;

    const int N = in_sizes[0];  // B = 1, N = 1024
    dim3 grid((N + NI - 1) / NI);
    relpos_kernel<<<grid, NTHREADS, 0, stream>>>(asym, res, ent, tok, sym, W, out, N);
}

// Round 2
// 532.043 us; speedup vs baseline: 1.0015x; 1.0015x over previous
//
#include <hip/hip_runtime.h>

// RelativePositionEncoding: O[i,j,c] = Wt[dres][c] + Wt[66+dtok][c]
//                                    + same_entity*Wt[132][c] + Wt[133+dchain][c]
// Wt[b][c] = W[c*139 + b]. Pure gather+add; store-BW bound (537 MB fp32 out,
// floor ~85 us @ 6.3 TB/s).
//
// R6->R7: single-variable A/B. R5 (2048 blk, c-split) and R6 (512 blk, merged)
// measured IDENTICAL (531 vs 533 us) -> bottleneck is invariant between them.
// Inferred kernel time ~190 us = 2.8 TB/s effective store BW, while the
// harness's plain-store fill hits 6.33 TB/s on the same buffer. The shared
// suspect is __builtin_nontemporal_store (L2-bypass can kill write-combining
// efficiency). This round: NT store -> plain store. Everything else identical.

#define R_MAX 32
#define NO_BINS 139
#define C_Z 128
#define N_MAX 1024     // harness N = 1024
#define WSTRIDE 132    // padded LDS row stride (words); 132%32=4, 16B-aligned rows
#define NI 2           // i-rows per block
#define NTHREADS 512

typedef float v4f __attribute__((ext_vector_type(4)));

__device__ __forceinline__ int make_pack(int ai, int ri, int ei, int ti, int si,
                                         int aj, int rj, int ej, int tj, int sj)
{
    const bool sc = (ai == aj);
    const bool sr = (ri == rj);
    const bool se = (ei == ej);

    int dr = min(max(ri - rj + R_MAX, 0), 2 * R_MAX);
    if (!sc) dr = 2 * R_MAX + 1;                    // 65
    int dt = min(max(ti - tj + R_MAX, 0), 2 * R_MAX);
    if (!(sc && sr)) dt = 2 * R_MAX + 1;            // 65
    int dc = min(max(si - sj + 2, 0), 4);
    if (!se) dc = 5;

    return dr | ((66 + dt) << 7) | ((133 + dc) << 15) | ((se ? 1 : 0) << 23);
}

__global__ __launch_bounds__(NTHREADS) void relpos_kernel(
    const int* __restrict__ asym, const int* __restrict__ res,
    const int* __restrict__ ent,  const int* __restrict__ tok,
    const int* __restrict__ sym,  const float* __restrict__ W,
    float* __restrict__ out, int N)
{
    __shared__ float wt[NO_BINS * WSTRIDE];  // 73,392 B: wt[b*132 + c]
    __shared__ int   jb_pack[N_MAX];         //  4,096 B

    const int tid = threadIdx.x;
    const int i0  = blockIdx.x * NI;

    // --- stage full W: coalesced float4 reads of contiguous W[c*139+b],
    //     transposed padded LDS writes (8-way write conflict, cheap) ---
    for (int q = tid; q < (C_Z * NO_BINS) / 4; q += NTHREADS) {  // 4448 float4
        const v4f v = *(const v4f*)(W + 4 * q);
        const int e = 4 * q;
#pragma unroll
        for (int k = 0; k < 4; ++k) {
            const int ee = e + k;
            const int c  = ee / NO_BINS;        // magic-mul div
            const int b  = ee - c * NO_BINS;
            wt[b * WSTRIDE + c] = v[k];
        }
    }

    // --- per-thread j attributes held in registers across the i-loop ---
    const int j0 = tid, j1 = tid + NTHREADS;
    const int rj0 = res[j0], tj0 = tok[j0], aj0 = asym[j0],
              ej0 = ent[j0], sj0 = sym[j0];
    int rj1 = 0, tj1 = 0, aj1 = 0, ej1 = 0, sj1 = 0;
    const bool has1 = (j1 < N);
    if (has1) { rj1 = res[j1]; tj1 = tok[j1]; aj1 = asym[j1];
                ej1 = ent[j1]; sj1 = sym[j1]; }

    const int c4 = (tid & 31) * 4;  // lane's 4-float slice within the 128-c row
    const int jl = tid >> 5;        // 0..15: j within chunk

    for (int ii = 0; ii < NI; ++ii) {
        const int i = i0 + ii;
        if (i >= N) break;

        // i-side scalars (block-uniform)
        const int ai = asym[i], ri = res[i], ei = ent[i], ti = tok[i], si = sym[i];

        __syncthreads();  // wt staged (ii==0) / prior main-loop pack reads done
        jb_pack[j0] = make_pack(ai, ri, ei, ti, si, aj0, rj0, ej0, tj0, sj0);
        if (has1)
            jb_pack[j1] = make_pack(ai, ri, ei, ti, si, aj1, rj1, ej1, tj1, sj1);
        __syncthreads();

        const v4f entv = *(const v4f*)&wt[132 * WSTRIDE + c4];
        float* po = out + ((size_t)i * N + jl) * C_Z + c4;

        // --- main loop: LDS-only reads, one contiguous plain store ---
        for (int jb = 0; jb < N; jb += 16) {
            const int pk   = jb_pack[jb + jl];   // broadcast within 32-lane group
            const int rowR = pk & 127;
            const int rowT = (pk >> 7) & 255;
            const int rowC = (pk >> 15) & 255;
            const float se = (pk >> 23) ? 1.0f : 0.0f;

            const v4f r0 = *(const v4f*)&wt[rowR * WSTRIDE + c4];
            const v4f t0 = *(const v4f*)&wt[rowT * WSTRIDE + c4];
            const v4f k0 = *(const v4f*)&wt[rowC * WSTRIDE + c4];

            v4f o;
            o.x = fmaf(se, entv.x, r0.x + t0.x + k0.x);
            o.y = fmaf(se, entv.y, r0.y + t0.y + k0.y);
            o.z = fmaf(se, entv.z, r0.z + t0.z + k0.z);
            o.w = fmaf(se, entv.w, r0.w + t0.w + k0.w);

            // 16B/lane; wave64 writes 1024B fully contiguous. PLAIN store:
            // route through L2 like the 6.3 TB/s harness fill (A/B vs nt).
            *(v4f*)po = o;
            po += 16 * C_Z;
        }
    }
}

extern "C" void kernel_launch(void* const* d_in, const int* in_sizes, int n_in,
                              void* d_out, int out_size, void* d_ws, size_t ws_size,
                              hipStream_t stream) {
    const int*   asym = (const int*)d_in[0];
    const int*   res  = (const int*)d_in[1];
    const int*   ent  = (const int*)d_in[2];
    const int*   tok  = (const int*)d_in[3];
    const int*   sym  = (const int*)d_in[4];
    const float* W    = (const float*)d_in[5];
    float* out = (float*)d_out;

    const int N = in_sizes[0];  // B = 1, N = 1024
    dim3 grid((N + NI - 1) / NI);
    relpos_kernel<<<grid, NTHREADS, 0, stream>>>(asym, res, ent, tok, sym, W, out, N);
}